// Round 13
// baseline (1281.568 us; speedup 1.0000x reference)
//
#include <hip/hip_runtime.h>

#define NCB 9
#define KCB 1024
#define CD 8
#define DD 64
#define TT 32768
#define BB 4

#define ZQ_SZ (BB*DD*TT)              // 8388608
#define CODES_OFF ZQ_SZ
#define CODES_SZ (BB*NCB*TT)          // 1179648
#define LAT_OFF (CODES_OFF + CODES_SZ)
#define LAT_SZ (BB*NCB*CD*TT)         // 9437184
#define LOSS_OFF (LAT_OFF + LAT_SZ)   // 19005440

// ---- d_ws byte layout ----
#define OFF_CBSPLIT  0          // 9216 codes * 32B (bf16 hi[8]|lo[8]) = 294912
#define OFF_CBN64    294912     // 73728 f64  = 589824
#define OFF_SCBK64   884736     // 9216 f64   = 73728
#define OFF_WIN64    958464     // 4608 f64   = 36864
#define OFF_WOUT64   995328     // 4608 f64   = 36864
#define OFF_BIN64    1032192    // 72 f64     = 576
#define OFF_BOUT64   1032768    // 576 f64    = 4608
#define OFF_LOSSPART 1037376    // 2048 f64   = 16384 (end 1053760)

#define MARGIN 1e-4f

typedef __attribute__((ext_vector_type(8))) short short8;
typedef __attribute__((ext_vector_type(4))) float f32x4;

__device__ __forceinline__ unsigned bf16rtn(float x) {
  unsigned u = __float_as_uint(x);
  return (u + 0x7fffu + ((u >> 16) & 1u)) >> 16;   // RTN bf16 (no NaN inputs here)
}

__global__ void prep_cb(const float* __restrict__ cb,
                        unsigned* __restrict__ cbsplit,
                        double* __restrict__ cbn64, double* __restrict__ scbk64) {
  int r = blockIdx.x * blockDim.x + threadIdx.x;
  if (r >= NCB * KCB) return;
  double v[CD], s = 0.0;
#pragma unroll
  for (int c = 0; c < CD; c++) { v[c] = (double)cb[r*CD + c]; s += v[c]*v[c]; }
  double den = fmax(sqrt(s), 1e-12);
  double s2 = 0.0;
  float of[CD];
#pragma unroll
  for (int c = 0; c < CD; c++) {
    double o = v[c] / den;
    cbn64[r*CD + c] = o;
    of[c] = (float)o;
    s2 += o*o;
  }
  scbk64[r] = s2;
  unsigned hp[4], lp[4];
#pragma unroll
  for (int c2 = 0; c2 < 4; c2++) {
    float f0 = of[2*c2], f1 = of[2*c2+1];
    unsigned h0 = bf16rtn(f0), h1 = bf16rtn(f1);
    float g0 = f0 - __uint_as_float(h0 << 16);
    float g1 = f1 - __uint_as_float(h1 << 16);
    unsigned l0 = bf16rtn(g0), l1 = bf16rtn(g1);
    hp[c2] = h0 | (h1 << 16);
    lp[c2] = l0 | (l1 << 16);
  }
  int4* dst = (int4*)(cbsplit + (size_t)r*8);
  dst[0] = make_int4((int)hp[0], (int)hp[1], (int)hp[2], (int)hp[3]);
  dst[1] = make_int4((int)lp[0], (int)lp[1], (int)lp[2], (int)lp[3]);
}

__global__ void prep_w(const float* __restrict__ W_in, const float* __restrict__ b_in,
                       const float* __restrict__ W_out, const float* __restrict__ b_out,
                       double* __restrict__ Win64, double* __restrict__ bin64,
                       double* __restrict__ Wout64, double* __restrict__ bout64) {
  int i = blockIdx.x * blockDim.x + threadIdx.x;
  if (i < NCB*CD*DD) Win64[i]  = (double)W_in[i];
  if (i < NCB*CD*DD) Wout64[i] = (double)W_out[i];
  if (i < NCB*CD)    bin64[i]  = (double)b_in[i];
  if (i < NCB*DD)    bout64[i] = (double)b_out[i];
}

// top-2 merge of two (best,best2,idx) triples over DISJOINT candidate sets;
// tie -> smaller index.
#define MERGE(bA,b2A,iA, bB,b2B,iB) { \
  float nb2_ = fmaxf(fminf((bA),(bB)), fmaxf((b2A),(b2B))); \
  bool tk_ = ((bB) > (bA)) || ((bB) == (bA) && (iB) < (iA)); \
  (bA) = fmaxf((bA),(bB)); (b2A) = nb2_; (iA) = tk_ ? (iB) : (iA); }

// Wave = 16 positions (one MFMA B-group), 64 MFMA/layer. f64 chain split
// 4-way: lane g*16+q owns d-channels [16g,16g+16) of position q; in_proj
// reduced via xor16/32 (bitwise exact). 2048 blocks -> 4 blocks/CU (32.8KB
// LDS) x 4 waves = 4 waves/SIMD (R12 was grid-capped at 2).
// __launch_bounds__(256,2): the empirically-clean VGPR=128 config.
__global__ __launch_bounds__(256, 2) void rvq_kernel(
    const float* __restrict__ x,
    const float* __restrict__ cb,
    const double* __restrict__ Win64,
    const double* __restrict__ bin64,
    const double* __restrict__ Wout64,
    const double* __restrict__ bout64,
    const unsigned* __restrict__ cbsplit,
    const double* __restrict__ cbn64,
    const double* __restrict__ scbk64,
    float* __restrict__ out,
    double* __restrict__ loss_part) {
  __shared__ __align__(16) char ldsbuf[32768];
  __shared__ double wsum[4];

  const int lane = threadIdx.x & 63;
  const int wv   = threadIdx.x >> 6;
  const int q    = lane & 15;           // position within wave
  const int g    = lane >> 4;           // chain-split / k-octet group
  const int p    = blockIdx.x * 64 + wv * 16 + q;
  const int b    = p >> 15;             // TT = 2^15
  const int t    = p & (TT - 1);
  const int dbase = g * 16;

  // my 16 D-channels of position q's f64 residual chain
  double r[16];
#pragma unroll
  for (int d = 0; d < 16; d++) r[d] = (double)x[(b*DD + dbase + d)*TT + t];

  double lacc = 0.0;

#pragma unroll 1
  for (int i = 0; i < NCB; i++) {
    // ---- stage split codebook i into LDS
    __syncthreads();
    {
      const float4* __restrict__ src = (const float4*)(cbsplit + (size_t)i*KCB*8);
      float4* __restrict__ dst = (float4*)ldsbuf;
#pragma unroll
      for (int c0 = 0; c0 < 8; c0++)
        dst[c0*256 + threadIdx.x] = src[c0*256 + threadIdx.x];
    }
    __syncthreads();

    // ---- in_proj (f64): partial over my 16 d's, xor16+32 reduce
    double ze[CD];
    {
      const double* __restrict__ W = Win64 + i*CD*DD + dbase;
#pragma unroll
      for (int c = 0; c < CD; c++) {
        double acc = 0.0;
#pragma unroll
        for (int d = 0; d < 16; d++)
          acc = fma(W[c*DD + d], r[d], acc);
        ze[c] = acc;
      }
#pragma unroll
      for (int c = 0; c < CD; c++) {
        ze[c] += __shfl_xor(ze[c], 16, 64);
        ze[c] += __shfl_xor(ze[c], 32, 64);
        ze[c] += bin64[i*CD + c];
      }
    }

    // ---- normalize; f32 enc
    double s0 = 0.0;
#pragma unroll
    for (int c = 0; c < CD; c++) s0 = fma(ze[c], ze[c], s0);
    double inv = 1.0 / fmax(sqrt(s0), 1e-12);
    float encf[CD];
#pragma unroll
    for (int c = 0; c < CD; c++) encf[c] = (float)(ze[c] * inv);

    // ---- latents (lane g writes channels 2g, 2g+1)
#pragma unroll
    for (int cc = 0; cc < 2; cc++)
      out[LAT_OFF + (b*NCB*CD + i*CD + 2*g + cc)*TT + t] = (float)ze[2*g + cc];

    // ---- pack enc hi/lo bf16; B-fragment via shfl from lane q (h/l then select)
    short8 bf8;
    {
      unsigned hp[4], lp[4];
#pragma unroll
      for (int c2 = 0; c2 < 4; c2++) {
        float f0 = encf[2*c2], f1 = encf[2*c2+1];
        unsigned h0 = bf16rtn(f0), h1 = bf16rtn(f1);
        float g0 = f0 - __uint_as_float(h0 << 16);
        float g1 = f1 - __uint_as_float(h1 << 16);
        unsigned l0 = bf16rtn(g0), l1 = bf16rtn(g1);
        hp[c2] = h0 | (h1 << 16);
        lp[c2] = l0 | (l1 << 16);
      }
      unsigned bj[4];
#pragma unroll
      for (int j = 0; j < 4; j++) {
        unsigned hj = __shfl((int)hp[j], q, 64);
        unsigned lj = __shfl((int)lp[j], q, 64);
        bj[j] = (g & 1) ? lj : hj;
      }
      int4 bi4 = make_int4((int)bj[0], (int)bj[1], (int)bj[2], (int)bj[3]);
      bf8 = __builtin_bit_cast(short8, bi4);
    }

    // ---- MFMA scan: 64 tiles x 16 codes, C col=q, row=g*4+reg
    const char* abase = ldsbuf + q*32 + ((g >> 1) << 4);
    float bq0 = -3.4e38f, bq1 = -3.4e38f, bq2 = -3.4e38f, bq3 = -3.4e38f;
    float q20 = -3.4e38f, q21 = -3.4e38f, q22 = -3.4e38f, q23 = -3.4e38f;
    int iq0 = 0, iq1 = 0, iq2 = 0, iq3 = 0;
    const f32x4 zero = {0.f, 0.f, 0.f, 0.f};
    const int lanebase = g * 4;
#pragma unroll 4
    for (int ct = 0; ct < 64; ct++) {
      int4 ai4 = *(const int4*)(abase + ct*512);
      short8 af8 = __builtin_bit_cast(short8, ai4);
      f32x4 Cv = __builtin_amdgcn_mfma_f32_16x16x32_bf16(af8, bf8, zero, 0, 0, 0);
      int kb = ct*16 + lanebase;
      float d0 = Cv[0], d1 = Cv[1], d2 = Cv[2], d3 = Cv[3];
      float ob;
      ob = bq0; q20 = __builtin_amdgcn_fmed3f(ob, q20, d0);
      bq0 = fmaxf(ob, d0); iq0 = (d0 > ob) ? (kb + 0) : iq0;
      ob = bq1; q21 = __builtin_amdgcn_fmed3f(ob, q21, d1);
      bq1 = fmaxf(ob, d1); iq1 = (d1 > ob) ? (kb + 1) : iq1;
      ob = bq2; q22 = __builtin_amdgcn_fmed3f(ob, q22, d2);
      bq2 = fmaxf(ob, d2); iq2 = (d2 > ob) ? (kb + 2) : iq2;
      ob = bq3; q23 = __builtin_amdgcn_fmed3f(ob, q23, d3);
      bq3 = fmaxf(ob, d3); iq3 = (d3 > ob) ? (kb + 3) : iq3;
    }

    // in-lane merges, then cross-lane (xor16, xor32) -> full top-2 for position q
    MERGE(bq0, q20, iq0, bq1, q21, iq1);
    MERGE(bq2, q22, iq2, bq3, q23, iq3);
    MERGE(bq0, q20, iq0, bq2, q22, iq2);
#pragma unroll
    for (int m = 16; m <= 32; m <<= 1) {
      float obm  = __shfl_xor(bq0, m, 64);
      float ob2m = __shfl_xor(q20, m, 64);
      int   oim  = __shfl_xor(iq0, m, 64);
      MERGE(bq0, q20, iq0, obm, ob2m, oim);
    }
    int bidxF = iq0;
    bool trigF = (bq0 - q20 < MARGIN);

    // ---- near-tie: cooperative f64 rescan (one pass per triggered position)
    {
      unsigned long long bal = __ballot(trigF) & 0xFFFFull;
      while (bal) {
        int j = __builtin_ctzll(bal);
        bal &= bal - 1;
        double invb = __shfl(inv, j, 64);
        double encb[CD], se = 0.0;
#pragma unroll
        for (int c = 0; c < CD; c++) {
          encb[c] = __shfl(ze[c], j, 64) * invb;
          se = fma(encb[c], encb[c], se);
        }
        const double* __restrict__ cbr = cbn64 + (size_t)i*KCB*CD;
        const double* __restrict__ s64 = scbk64 + i*KCB;
        double bd = 1e300;
        int bk = 0;
#pragma unroll 2
        for (int it = 0; it < 16; it++) {
          int k = it*64 + lane;
          const double* row = cbr + (size_t)k*CD;
          double dot = 0.0;
#pragma unroll
          for (int c = 0; c < CD; c++) dot = fma(encb[c], row[c], dot);
          double dist = fma(-2.0, dot, se) + s64[k];
          if (dist < bd) { bd = dist; bk = k; }       // ascending k -> first index
        }
#pragma unroll
        for (int m = 1; m <= 32; m <<= 1) {
          double od = __shfl_xor(bd, m, 64);
          int    ok = __shfl_xor(bk, m, 64);
          bool take = (od < bd) || (od == bd && ok < bk);
          bd = take ? od : bd;
          bk = take ? ok : bk;
        }
        if (q == j) bidxF = bk;
      }
    }

    // ---- gather raw codebook row (uniform across the 4 g-lanes of q)
    const float4* __restrict__ qrow = (const float4*)(cb + (size_t)(i*KCB + bidxF)*CD);
    float4 q0 = qrow[0], q1 = qrow[1];
    double zq[CD] = {(double)q0.x, (double)q0.y, (double)q0.z, (double)q0.w,
                     (double)q1.x, (double)q1.y, (double)q1.z, (double)q1.w};

    // ---- loss once per position (g==0)
    if (g == 0) {
#pragma unroll
      for (int c = 0; c < CD; c++) {
        double dlt = ze[c] - zq[c];
        lacc = fma(dlt, dlt, lacc);
      }
    }

    // ---- out_proj (f64) on my 16 d's + residual update
    {
      const double* __restrict__ Wo = Wout64 + (i*DD + dbase)*CD;
#pragma unroll
      for (int d = 0; d < 16; d++) {
        double acc = bout64[i*DD + dbase + d];
#pragma unroll
        for (int c = 0; c < CD; c++)
          acc = fma(Wo[d*CD + c], zq[c], acc);
        r[d] -= acc;
      }
    }

    // ---- codes (g==0)
    if (g == 0) out[CODES_OFF + (b*NCB + i)*TT + t] = (float)bidxF;
  }

  // ---- z_q = x - residual_final (my 16 d's)
#pragma unroll
  for (int d = 0; d < 16; d++)
    out[(b*DD + dbase + d)*TT + t] =
        (float)((double)x[(b*DD + dbase + d)*TT + t] - r[d]);

  // ---- deterministic loss reduction (g!=0 lanes hold 0)
#pragma unroll
  for (int off = 32; off > 0; off >>= 1)
    lacc += __shfl_down(lacc, off, 64);
  if ((threadIdx.x & 63) == 0) wsum[wv] = lacc;
  __syncthreads();
  if (threadIdx.x == 0)
    loss_part[blockIdx.x] = wsum[0] + wsum[1] + wsum[2] + wsum[3];
}

__global__ void loss_final(const double* __restrict__ loss_part,
                           float* __restrict__ out) {
  __shared__ double sh[256];
  double s = 0.0;
#pragma unroll
  for (int i = 0; i < 8; i++) s += loss_part[threadIdx.x + i*256];
  sh[threadIdx.x] = s;
  __syncthreads();
  for (int off = 128; off > 0; off >>= 1) {
    if (threadIdx.x < off) sh[threadIdx.x] += sh[threadIdx.x + off];
    __syncthreads();
  }
  if (threadIdx.x == 0) {
    double v = sh[0] / ((double)NCB * (double)BB * (double)CD * (double)TT);
    out[LOSS_OFF]     = (float)v;   // commit
    out[LOSS_OFF + 1] = (float)v;   // cb_loss (equal in forward value)
  }
}

extern "C" void kernel_launch(void* const* d_in, const int* in_sizes, int n_in,
                              void* d_out, int out_size, void* d_ws, size_t ws_size,
                              hipStream_t stream) {
  const float* x     = (const float*)d_in[0];
  const float* W_in  = (const float*)d_in[1];
  const float* b_in  = (const float*)d_in[2];
  const float* cb    = (const float*)d_in[3];
  const float* W_out = (const float*)d_in[4];
  const float* b_out = (const float*)d_in[5];
  float* out = (float*)d_out;

  char* ws = (char*)d_ws;
  unsigned* cbsplit = (unsigned*)(ws + OFF_CBSPLIT);
  double* cbn64  = (double*)(ws + OFF_CBN64);
  double* scbk64 = (double*)(ws + OFF_SCBK64);
  double* Win64  = (double*)(ws + OFF_WIN64);
  double* Wout64 = (double*)(ws + OFF_WOUT64);
  double* bin64  = (double*)(ws + OFF_BIN64);
  double* bout64 = (double*)(ws + OFF_BOUT64);
  double* loss_part = (double*)(ws + OFF_LOSSPART);

  prep_cb<<<(NCB*KCB + 255)/256, 256, 0, stream>>>(cb, cbsplit, cbn64, scbk64);
  prep_w<<<(NCB*CD*DD + 255)/256, 256, 0, stream>>>(W_in, b_in, W_out, b_out,
                                                    Win64, bin64, Wout64, bout64);
  rvq_kernel<<<2048, 256, 0, stream>>>(x, cb, Win64, bin64, Wout64, bout64,
                                       cbsplit, cbn64, scbk64, out, loss_part);
  loss_final<<<1, 256, 0, stream>>>(loss_part, out);
}

// Round 14
// 543.239 us; speedup vs baseline: 2.3591x; 2.3591x over previous
//
#include <hip/hip_runtime.h>

#define NCB 9
#define KCB 1024
#define CD 8
#define DD 64
#define TT 32768
#define BB 4

#define ZQ_SZ (BB*DD*TT)              // 8388608
#define CODES_OFF ZQ_SZ
#define CODES_SZ (BB*NCB*TT)          // 1179648
#define LAT_OFF (CODES_OFF + CODES_SZ)
#define LAT_SZ (BB*NCB*CD*TT)         // 9437184
#define LOSS_OFF (LAT_OFF + LAT_SZ)   // 19005440

// ---- d_ws byte layout ----
#define OFF_CBSPLIT  0          // 9216 codes * 32B (bf16 hi[8]|lo[8]) = 294912
#define OFF_CBN64    294912     // 73728 f64  = 589824
#define OFF_SCBK64   884736     // 9216 f64   = 73728
#define OFF_WIN64    958464     // 4608 f64   = 36864
#define OFF_WOUT64   995328     // 4608 f64   = 36864
#define OFF_BIN64    1032192    // 72 f64     = 576
#define OFF_BOUT64   1032768    // 576 f64    = 4608
#define OFF_LOSSPART 1037376    // 256 f64    = 2048

#define MARGIN 1e-4f

typedef __attribute__((ext_vector_type(8))) short short8;
typedef __attribute__((ext_vector_type(4))) float f32x4;

__device__ __forceinline__ unsigned bf16rtn(float x) {
  unsigned u = __float_as_uint(x);
  return (u + 0x7fffu + ((u >> 16) & 1u)) >> 16;   // RTN bf16 (no NaN inputs here)
}

__global__ void prep_cb(const float* __restrict__ cb,
                        unsigned* __restrict__ cbsplit,
                        double* __restrict__ cbn64, double* __restrict__ scbk64) {
  int r = blockIdx.x * blockDim.x + threadIdx.x;
  if (r >= NCB * KCB) return;
  double v[CD], s = 0.0;
#pragma unroll
  for (int c = 0; c < CD; c++) { v[c] = (double)cb[r*CD + c]; s += v[c]*v[c]; }
  double den = fmax(sqrt(s), 1e-12);
  double s2 = 0.0;
  float of[CD];
#pragma unroll
  for (int c = 0; c < CD; c++) {
    double o = v[c] / den;
    cbn64[r*CD + c] = o;
    of[c] = (float)o;
    s2 += o*o;
  }
  scbk64[r] = s2;
  unsigned hp[4], lp[4];
#pragma unroll
  for (int c2 = 0; c2 < 4; c2++) {
    float f0 = of[2*c2], f1 = of[2*c2+1];
    unsigned h0 = bf16rtn(f0), h1 = bf16rtn(f1);
    float g0 = f0 - __uint_as_float(h0 << 16);
    float g1 = f1 - __uint_as_float(h1 << 16);
    unsigned l0 = bf16rtn(g0), l1 = bf16rtn(g1);
    hp[c2] = h0 | (h1 << 16);
    lp[c2] = l0 | (l1 << 16);
  }
  int4* dst = (int4*)(cbsplit + (size_t)r*8);
  dst[0] = make_int4((int)hp[0], (int)hp[1], (int)hp[2], (int)hp[3]);
  dst[1] = make_int4((int)lp[0], (int)lp[1], (int)lp[2], (int)lp[3]);
}

__global__ void prep_w(const float* __restrict__ W_in, const float* __restrict__ b_in,
                       const float* __restrict__ W_out, const float* __restrict__ b_out,
                       double* __restrict__ Win64, double* __restrict__ bin64,
                       double* __restrict__ Wout64, double* __restrict__ bout64) {
  int i = blockIdx.x * blockDim.x + threadIdx.x;
  if (i < NCB*CD*DD) Win64[i]  = (double)W_in[i];
  if (i < NCB*CD*DD) Wout64[i] = (double)W_out[i];
  if (i < NCB*CD)    bin64[i]  = (double)b_in[i];
  if (i < NCB*DD)    bout64[i] = (double)b_out[i];
}

// top-2 merge of two (best,best2,idx) triples over DISJOINT candidate sets;
// tie -> smaller index.
#define MERGE(bA,b2A,iA, bB,b2B,iB) { \
  float nb2_ = fmaxf(fminf((bA),(bB)), fmaxf((b2A),(b2B))); \
  bool tk_ = ((bB) > (bA)) || ((bB) == (bA) && (iB) < (iA)); \
  (bA) = fmaxf((bA),(bB)); (b2A) = nb2_; (iA) = tk_ ? (iB) : (iA); }

// R12 structure (thread-per-position, wave = 64 positions, 4 pt-groups) with:
//  - 512-thread blocks: 8 waves share the 32KB LDS codebook -> 2 blocks/CU
//    (49KB LDS) x 8 waves = 16 waves/CU = 4 waves/SIMD (R12 was grid-capped
//    at 2). Per-thread register structure byte-identical to R12 (VGPR=128).
//  - LDS chunk swizzle c ^= (c>>3)&3: A-fragment rows at stride-32B were a
//    4-way bank conflict (R12/R13: 1.9e7 SQ_LDS_BANK_CONFLICT); the XOR field
//    is ct-invariant so it folds into the precomputed lane base (0 extra VALU).
// __launch_bounds__(512,2): same 2-waves/EU budget as the proven (256,2).
__global__ __launch_bounds__(512, 2) void rvq_kernel(
    const float* __restrict__ x,
    const float* __restrict__ cb,
    const double* __restrict__ Win64,
    const double* __restrict__ bin64,
    const double* __restrict__ Wout64,
    const double* __restrict__ bout64,
    const unsigned* __restrict__ cbsplit,
    const double* __restrict__ cbn64,
    const double* __restrict__ scbk64,
    float* __restrict__ out,
    double* __restrict__ loss_part) {
  // 32 KB swizzled codebook + 8 waves x 2 KB B-exchange
  __shared__ __align__(16) char ldsbuf[32768 + 16384];
  __shared__ double wsum[8];

  const int lane = threadIdx.x & 63;
  const int wv   = threadIdx.x >> 6;
  const int tid  = blockIdx.x * 512 + threadIdx.x;
  const int b = tid >> 15;            // TT = 2^15
  const int t = tid & (TT - 1);
  const int lanebase = (lane >> 4) * 4;          // C-layout row base
  char* bex = ldsbuf + 32768 + wv * 2048;

  double r[DD];
#pragma unroll
  for (int d = 0; d < DD; d++) r[d] = (double)x[(b*DD + d)*TT + t];

  double lacc = 0.0;

  // swizzled staging index: chunk c0*512+tid -> xor field = (tid>>3)&3
  const int stid = (int)threadIdx.x ^ (((int)threadIdx.x >> 3) & 3);
  // swizzled A-fragment base chunk: c0 = 2q + khalf, xor field = (c0>>3)&3
  const int ac0 = 2*(lane & 15) + ((lane >> 4) >> 1);
  const char* abase = ldsbuf + (size_t)(ac0 ^ ((ac0 >> 3) & 3)) * 16;

#pragma unroll 1
  for (int i = 0; i < NCB; i++) {
    // ---- stage split codebook i into LDS (swizzled chunks)
    __syncthreads();
    {
      const float4* __restrict__ src = (const float4*)(cbsplit + (size_t)i*KCB*8);
      float4* __restrict__ dst = (float4*)ldsbuf;
#pragma unroll
      for (int c0 = 0; c0 < 4; c0++)
        dst[c0*512 + stid] = src[c0*512 + threadIdx.x];
    }
    __syncthreads();

    // ---- in_proj (f64)
    double ze[CD];
#pragma unroll
    for (int c = 0; c < CD; c++) ze[c] = bin64[i*CD + c];
#pragma unroll
    for (int c = 0; c < CD; c++) {
#pragma unroll
      for (int d = 0; d < DD; d++)
        ze[c] = fma(Win64[(i*CD + c)*DD + d], r[d], ze[c]);
    }

    // ---- normalize; f32 enc
    double s0 = 0.0;
#pragma unroll
    for (int c = 0; c < CD; c++) s0 = fma(ze[c], ze[c], s0);
    double inv = 1.0 / fmax(sqrt(s0), 1e-12);
    float encf[CD];
#pragma unroll
    for (int c = 0; c < CD; c++) encf[c] = (float)(ze[c] * inv);

    // ---- latents
#pragma unroll
    for (int c = 0; c < CD; c++)
      out[LAT_OFF + (b*NCB*CD + i*CD + c)*TT + t] = (float)ze[c];

    // ---- pack enc hi/lo bf16, exchange through per-wave LDS (B transpose)
    {
      unsigned hp[4], lp[4];
#pragma unroll
      for (int c2 = 0; c2 < 4; c2++) {
        float f0 = encf[2*c2], f1 = encf[2*c2+1];
        unsigned h0 = bf16rtn(f0), h1 = bf16rtn(f1);
        float g0 = f0 - __uint_as_float(h0 << 16);
        float g1 = f1 - __uint_as_float(h1 << 16);
        unsigned l0 = bf16rtn(g0), l1 = bf16rtn(g1);
        hp[c2] = h0 | (h1 << 16);
        lp[c2] = l0 | (l1 << 16);
      }
      *(int4*)(bex + lane*32)      = make_int4((int)hp[0],(int)hp[1],(int)hp[2],(int)hp[3]);
      *(int4*)(bex + lane*32 + 16) = make_int4((int)lp[0],(int)lp[1],(int)lp[2],(int)lp[3]);
    }

    int bidxF = 0;
    bool trigF = false;

#pragma unroll 1
    for (int pt = 0; pt < 4; pt++) {
      // B-fragment: col=lane&15 -> position pt*16+(lane&15); k-octet -> [hi,lo,hi,lo]
      int4 bi4 = *(const int4*)(bex + (pt*16 + (lane & 15))*32 + ((lane >> 4) & 1)*16);
      short8 bf8 = __builtin_bit_cast(short8, bi4);

      float bq0 = -3.4e38f, bq1 = -3.4e38f, bq2 = -3.4e38f, bq3 = -3.4e38f;
      float q20 = -3.4e38f, q21 = -3.4e38f, q22 = -3.4e38f, q23 = -3.4e38f;
      int iq0 = 0, iq1 = 0, iq2 = 0, iq3 = 0;
      const f32x4 zero = {0.f, 0.f, 0.f, 0.f};

#pragma unroll 4
      for (int ct = 0; ct < 64; ct++) {
        int4 ai4 = *(const int4*)(abase + ct*512);
        short8 af8 = __builtin_bit_cast(short8, ai4);
        f32x4 Cv = __builtin_amdgcn_mfma_f32_16x16x32_bf16(af8, bf8, zero, 0, 0, 0);
        int kb = ct*16 + lanebase;
        float d0 = Cv[0], d1 = Cv[1], d2 = Cv[2], d3 = Cv[3];
        float ob;
        ob = bq0; q20 = __builtin_amdgcn_fmed3f(ob, q20, d0);
        bq0 = fmaxf(ob, d0); iq0 = (d0 > ob) ? (kb + 0) : iq0;
        ob = bq1; q21 = __builtin_amdgcn_fmed3f(ob, q21, d1);
        bq1 = fmaxf(ob, d1); iq1 = (d1 > ob) ? (kb + 1) : iq1;
        ob = bq2; q22 = __builtin_amdgcn_fmed3f(ob, q22, d2);
        bq2 = fmaxf(ob, d2); iq2 = (d2 > ob) ? (kb + 2) : iq2;
        ob = bq3; q23 = __builtin_amdgcn_fmed3f(ob, q23, d3);
        bq3 = fmaxf(ob, d3); iq3 = (d3 > ob) ? (kb + 3) : iq3;
      }

      // in-lane q merges, then cross-lane (xor16, xor32)
      MERGE(bq0, q20, iq0, bq1, q21, iq1);
      MERGE(bq2, q22, iq2, bq3, q23, iq3);
      MERGE(bq0, q20, iq0, bq2, q22, iq2);
#pragma unroll
      for (int m = 16; m <= 32; m <<= 1) {
        float obm  = __shfl_xor(bq0, m, 64);
        float ob2m = __shfl_xor(q20, m, 64);
        int   oim  = __shfl_xor(iq0, m, 64);
        MERGE(bq0, q20, iq0, obm, ob2m, oim);
      }

      bool own = ((lane >> 4) == pt);
      bidxF = own ? iq0 : bidxF;
      trigF = own ? (bq0 - q20 < MARGIN) : trigF;
    }

    // ---- near-tie: cooperative f64 rescan (wave-parallel, ~1K cyc/trigger)
    {
      unsigned long long bal = __ballot(trigF);
      while (bal) {
        int j = __builtin_ctzll(bal);
        bal &= bal - 1;
        double invb = __shfl(inv, j, 64);
        double encb[CD], se = 0.0;
#pragma unroll
        for (int c = 0; c < CD; c++) {
          encb[c] = __shfl(ze[c], j, 64) * invb;
          se = fma(encb[c], encb[c], se);
        }
        const double* __restrict__ cbr = cbn64 + (size_t)i*KCB*CD;
        const double* __restrict__ s64 = scbk64 + i*KCB;
        double bd = 1e300;
        int bk = 0;
#pragma unroll 2
        for (int it = 0; it < 16; it++) {
          int k = it*64 + lane;
          const double* row = cbr + (size_t)k*CD;
          double dot = 0.0;
#pragma unroll
          for (int c = 0; c < CD; c++) dot = fma(encb[c], row[c], dot);
          double dist = fma(-2.0, dot, se) + s64[k];
          if (dist < bd) { bd = dist; bk = k; }       // ascending k -> first index
        }
#pragma unroll
        for (int m = 1; m <= 32; m <<= 1) {
          double od = __shfl_xor(bd, m, 64);
          int    ok = __shfl_xor(bk, m, 64);
          bool take = (od < bd) || (od == bd && ok < bk);
          bd = take ? od : bd;
          bk = take ? ok : bk;
        }
        if (lane == j) bidxF = bk;
      }
    }

    // ---- gather raw codebook row
    const float4* __restrict__ qrow = (const float4*)(cb + (size_t)(i*KCB + bidxF)*CD);
    float4 q0 = qrow[0], q1 = qrow[1];
    double zq[CD] = {(double)q0.x, (double)q0.y, (double)q0.z, (double)q0.w,
                     (double)q1.x, (double)q1.y, (double)q1.z, (double)q1.w};

    // ---- losses
#pragma unroll
    for (int c = 0; c < CD; c++) {
      double dlt = ze[c] - zq[c];
      lacc = fma(dlt, dlt, lacc);
    }

    // ---- out_proj (f64) + residual update
#pragma unroll
    for (int d = 0; d < DD; d++) {
      double acc = bout64[i*DD + d];
#pragma unroll
      for (int c = 0; c < CD; c++)
        acc = fma(Wout64[(i*DD + d)*CD + c], zq[c], acc);
      r[d] -= acc;
    }

    // ---- codes
    out[CODES_OFF + (b*NCB + i)*TT + t] = (float)bidxF;
  }

  // ---- z_q = x - residual_final
#pragma unroll
  for (int d = 0; d < DD; d++)
    out[(b*DD + d)*TT + t] = (float)((double)x[(b*DD + d)*TT + t] - r[d]);

  // ---- deterministic loss reduction
#pragma unroll
  for (int off = 32; off > 0; off >>= 1)
    lacc += __shfl_down(lacc, off, 64);
  if ((threadIdx.x & 63) == 0) wsum[wv] = lacc;
  __syncthreads();
  if (threadIdx.x == 0) {
    double s = 0.0;
#pragma unroll
    for (int w = 0; w < 8; w++) s += wsum[w];
    loss_part[blockIdx.x] = s;
  }
}

__global__ void loss_final(const double* __restrict__ loss_part,
                           float* __restrict__ out) {
  __shared__ double sh[256];
  sh[threadIdx.x] = loss_part[threadIdx.x];   // 256 blocks -> 256 partials
  __syncthreads();
  for (int off = 128; off > 0; off >>= 1) {
    if (threadIdx.x < off) sh[threadIdx.x] += sh[threadIdx.x + off];
    __syncthreads();
  }
  if (threadIdx.x == 0) {
    double v = sh[0] / ((double)NCB * (double)BB * (double)CD * (double)TT);
    out[LOSS_OFF]     = (float)v;   // commit
    out[LOSS_OFF + 1] = (float)v;   // cb_loss (equal in forward value)
  }
}

extern "C" void kernel_launch(void* const* d_in, const int* in_sizes, int n_in,
                              void* d_out, int out_size, void* d_ws, size_t ws_size,
                              hipStream_t stream) {
  const float* x     = (const float*)d_in[0];
  const float* W_in  = (const float*)d_in[1];
  const float* b_in  = (const float*)d_in[2];
  const float* cb    = (const float*)d_in[3];
  const float* W_out = (const float*)d_in[4];
  const float* b_out = (const float*)d_in[5];
  float* out = (float*)d_out;

  char* ws = (char*)d_ws;
  unsigned* cbsplit = (unsigned*)(ws + OFF_CBSPLIT);
  double* cbn64  = (double*)(ws + OFF_CBN64);
  double* scbk64 = (double*)(ws + OFF_SCBK64);
  double* Win64  = (double*)(ws + OFF_WIN64);
  double* Wout64 = (double*)(ws + OFF_WOUT64);
  double* bin64  = (double*)(ws + OFF_BIN64);
  double* bout64 = (double*)(ws + OFF_BOUT64);
  double* loss_part = (double*)(ws + OFF_LOSSPART);

  prep_cb<<<(NCB*KCB + 255)/256, 256, 0, stream>>>(cb, cbsplit, cbn64, scbk64);
  prep_w<<<(NCB*CD*DD + 255)/256, 256, 0, stream>>>(W_in, b_in, W_out, b_out,
                                                    Win64, bin64, Wout64, bout64);
  rvq_kernel<<<256, 512, 0, stream>>>(x, cb, Win64, bin64, Wout64, bout64,
                                      cbsplit, cbn64, scbk64, out, loss_part);
  loss_final<<<1, 256, 0, stream>>>(loss_part, out);
}

// Round 15
// 416.699 us; speedup vs baseline: 3.0755x; 1.3037x over previous
//
#include <hip/hip_runtime.h>

#define NCB 9
#define KCB 1024
#define CD 8
#define DD 64
#define TT 32768
#define BB 4

#define ZQ_SZ (BB*DD*TT)              // 8388608
#define CODES_OFF ZQ_SZ
#define CODES_SZ (BB*NCB*TT)          // 1179648
#define LAT_OFF (CODES_OFF + CODES_SZ)
#define LAT_SZ (BB*NCB*CD*TT)         // 9437184
#define LOSS_OFF (LAT_OFF + LAT_SZ)   // 19005440

// ---- d_ws byte layout ----
#define OFF_CBSPLIT  0          // 9216 codes * 32B (bf16 hi[8]|lo[8]) = 294912
#define OFF_CBN64    294912     // 73728 f64  = 589824
#define OFF_SCBK64   884736     // 9216 f64   = 73728
#define OFF_WIN64    958464     // 4608 f64   = 36864
#define OFF_WOUT64   995328     // 4608 f64   = 36864
#define OFF_BIN64    1032192    // 72 f64     = 576
#define OFF_BOUT64   1032768    // 576 f64    = 4608
#define OFF_LOSSPART 1037376    // 256 f64    = 2048

#define MARGIN 1.5e-4f

typedef __attribute__((ext_vector_type(8))) short short8;
typedef __attribute__((ext_vector_type(4))) float f32x4;

__device__ __forceinline__ unsigned bf16rtn(float x) {
  unsigned u = __float_as_uint(x);
  return (u + 0x7fffu + ((u >> 16) & 1u)) >> 16;   // RTN bf16 (no NaN inputs here)
}

__global__ void prep_cb(const float* __restrict__ cb,
                        unsigned* __restrict__ cbsplit,
                        double* __restrict__ cbn64, double* __restrict__ scbk64) {
  int r = blockIdx.x * blockDim.x + threadIdx.x;
  if (r >= NCB * KCB) return;
  double v[CD], s = 0.0;
#pragma unroll
  for (int c = 0; c < CD; c++) { v[c] = (double)cb[r*CD + c]; s += v[c]*v[c]; }
  double den = fmax(sqrt(s), 1e-12);
  double s2 = 0.0;
  float of[CD];
#pragma unroll
  for (int c = 0; c < CD; c++) {
    double o = v[c] / den;
    cbn64[r*CD + c] = o;
    of[c] = (float)o;
    s2 += o*o;
  }
  scbk64[r] = s2;
  unsigned hp[4], lp[4];
#pragma unroll
  for (int c2 = 0; c2 < 4; c2++) {
    float f0 = of[2*c2], f1 = of[2*c2+1];
    unsigned h0 = bf16rtn(f0), h1 = bf16rtn(f1);
    float g0 = f0 - __uint_as_float(h0 << 16);
    float g1 = f1 - __uint_as_float(h1 << 16);
    unsigned l0 = bf16rtn(g0), l1 = bf16rtn(g1);
    hp[c2] = h0 | (h1 << 16);
    lp[c2] = l0 | (l1 << 16);
  }
  int4* dst = (int4*)(cbsplit + (size_t)r*8);
  dst[0] = make_int4((int)hp[0], (int)hp[1], (int)hp[2], (int)hp[3]);
  dst[1] = make_int4((int)lp[0], (int)lp[1], (int)lp[2], (int)lp[3]);
}

__global__ void prep_w(const float* __restrict__ W_in, const float* __restrict__ b_in,
                       const float* __restrict__ W_out, const float* __restrict__ b_out,
                       double* __restrict__ Win64, double* __restrict__ bin64,
                       double* __restrict__ Wout64, double* __restrict__ bout64) {
  int i = blockIdx.x * blockDim.x + threadIdx.x;
  if (i < NCB*CD*DD) Win64[i]  = (double)W_in[i];
  if (i < NCB*CD*DD) Wout64[i] = (double)W_out[i];
  if (i < NCB*CD)    bin64[i]  = (double)b_in[i];
  if (i < NCB*DD)    bout64[i] = (double)b_out[i];
}

// top-2 merge of two (best,best2,idx) triples over DISJOINT candidate sets;
// tie -> smaller index.
#define MERGE(bA,b2A,iA, bB,b2B,iB) { \
  float nb2_ = fmaxf(fminf((bA),(bB)), fmaxf((b2A),(b2B))); \
  bool tk_ = ((bB) > (bA)) || ((bB) == (bA) && (iB) < (iA)); \
  (bA) = fmaxf((bA),(bB)); (b2A) = nb2_; (iA) = tk_ ? (iB) : (iA); }

// per-ct quad-max tracker update: m = max of 4 C-regs; kb = quad base index.
#define QSEL(Cv, bq, s2, kb, kbv) { \
  float m_ = fmaxf(fmaxf(fmaxf((Cv)[0],(Cv)[1]),(Cv)[2]),(Cv)[3]); \
  float ob_ = (bq); \
  (s2) = __builtin_amdgcn_fmed3f(ob_, (s2), m_); \
  (bq) = fmaxf(ob_, m_); \
  (kb) = (m_ > ob_) ? (kbv) : (kb); }

// R15: A-tile hoisted out of the pt-loop (64 ds_read_b128/layer, was 256;
// each read feeds 4 MFMAs) + quad-max SEL (6 ops/pt/ct, was 16) with exact
// post-scan 4-candidate resolution (f32 = hi+lo reconstruction, error ~1e-5
// covered by MARGIN). 512-thread blocks share one 32KB staged codebook.
__global__ __launch_bounds__(512, 2) void rvq_kernel(
    const float* __restrict__ x,
    const float* __restrict__ cb,
    const double* __restrict__ Win64,
    const double* __restrict__ bin64,
    const double* __restrict__ Wout64,
    const double* __restrict__ bout64,
    const unsigned* __restrict__ cbsplit,
    const double* __restrict__ cbn64,
    const double* __restrict__ scbk64,
    float* __restrict__ out,
    double* __restrict__ loss_part) {
  // 32 KB swizzled codebook + 8 waves x 2 KB B-exchange
  __shared__ __align__(16) char ldsbuf[32768 + 16384];
  __shared__ double wsum[8];

  const int lane = threadIdx.x & 63;
  const int wv   = threadIdx.x >> 6;
  const int tid  = blockIdx.x * 512 + threadIdx.x;
  const int b = tid >> 15;            // TT = 2^15
  const int t = tid & (TT - 1);
  const int lanebase = (lane >> 4) * 4;          // C-layout row-quad base
  char* bex = ldsbuf + 32768 + wv * 2048;

  double r[DD];
#pragma unroll
  for (int d = 0; d < DD; d++) r[d] = (double)x[(b*DD + d)*TT + t];

  double lacc = 0.0;

  // swizzled staging index (chunk swizzle c ^= (c>>3)&3)
  const int stid = (int)threadIdx.x ^ (((int)threadIdx.x >> 3) & 3);
  // A-fragment base chunk: c0 = 2*row + khalf  (row = lane&15, khalf = g>>1)
  const int ac0 = 2*(lane & 15) + ((lane >> 4) >> 1);
  const char* abase = ldsbuf + (size_t)(ac0 ^ ((ac0 >> 3) & 3)) * 16;

#pragma unroll 1
  for (int i = 0; i < NCB; i++) {
    // ---- stage split codebook i into LDS (swizzled chunks)
    __syncthreads();
    {
      const float4* __restrict__ src = (const float4*)(cbsplit + (size_t)i*KCB*8);
      float4* __restrict__ dst = (float4*)ldsbuf;
#pragma unroll
      for (int c0 = 0; c0 < 4; c0++)
        dst[c0*512 + stid] = src[c0*512 + threadIdx.x];
    }
    __syncthreads();

    // ---- in_proj (f64)
    double ze[CD];
#pragma unroll
    for (int c = 0; c < CD; c++) ze[c] = bin64[i*CD + c];
#pragma unroll
    for (int c = 0; c < CD; c++) {
#pragma unroll
      for (int d = 0; d < DD; d++)
        ze[c] = fma(Win64[(i*CD + c)*DD + d], r[d], ze[c]);
    }

    // ---- normalize; f32 enc
    double s0 = 0.0;
#pragma unroll
    for (int c = 0; c < CD; c++) s0 = fma(ze[c], ze[c], s0);
    double inv = 1.0 / fmax(sqrt(s0), 1e-12);
    float encf[CD];
#pragma unroll
    for (int c = 0; c < CD; c++) encf[c] = (float)(ze[c] * inv);

    // ---- latents
#pragma unroll
    for (int c = 0; c < CD; c++)
      out[LAT_OFF + (b*NCB*CD + i*CD + c)*TT + t] = (float)ze[c];

    // ---- pack enc hi/lo bf16, exchange through per-wave LDS (B transpose)
    {
      unsigned hp[4], lp[4];
#pragma unroll
      for (int c2 = 0; c2 < 4; c2++) {
        float f0 = encf[2*c2], f1 = encf[2*c2+1];
        unsigned h0 = bf16rtn(f0), h1 = bf16rtn(f1);
        float g0 = f0 - __uint_as_float(h0 << 16);
        float g1 = f1 - __uint_as_float(h1 << 16);
        unsigned l0 = bf16rtn(g0), l1 = bf16rtn(g1);
        hp[c2] = h0 | (h1 << 16);
        lp[c2] = l0 | (l1 << 16);
      }
      *(int4*)(bex + lane*32)      = make_int4((int)hp[0],(int)hp[1],(int)hp[2],(int)hp[3]);
      *(int4*)(bex + lane*32 + 16) = make_int4((int)lp[0],(int)lp[1],(int)lp[2],(int)lp[3]);
    }

    // ---- B-fragments for all 4 pt-groups (16 VGPR, held through the scan)
    short8 bf0, bf1, bf2, bf3;
    {
      const int boff = (lane & 15)*32 + ((lane >> 4) & 1)*16;
      bf0 = __builtin_bit_cast(short8, *(const int4*)(bex + boff));
      bf1 = __builtin_bit_cast(short8, *(const int4*)(bex + 512 + boff));
      bf2 = __builtin_bit_cast(short8, *(const int4*)(bex + 1024 + boff));
      bf3 = __builtin_bit_cast(short8, *(const int4*)(bex + 1536 + boff));
    }

    // ---- MFMA scan: one A-load per ct feeds 4 MFMAs; quad-max trackers
    float bq0=-3.4e38f, bq1=-3.4e38f, bq2=-3.4e38f, bq3=-3.4e38f;
    float s20=-3.4e38f, s21=-3.4e38f, s22=-3.4e38f, s23=-3.4e38f;
    int kb0=0, kb1=0, kb2=0, kb3=0;
    const f32x4 zero = {0.f, 0.f, 0.f, 0.f};
    int4 a_next = *(const int4*)(abase);
#pragma unroll 4
    for (int ct = 0; ct < 64; ct++) {
      int4 a_cur = a_next;
      if (ct < 63) a_next = *(const int4*)(abase + (ct + 1)*512);
      short8 af8 = __builtin_bit_cast(short8, a_cur);
      const int kbv = ct*16 + lanebase;
      f32x4 C0 = __builtin_amdgcn_mfma_f32_16x16x32_bf16(af8, bf0, zero, 0, 0, 0);
      QSEL(C0, bq0, s20, kb0, kbv);
      f32x4 C1 = __builtin_amdgcn_mfma_f32_16x16x32_bf16(af8, bf1, zero, 0, 0, 0);
      QSEL(C1, bq1, s21, kb1, kbv);
      f32x4 C2 = __builtin_amdgcn_mfma_f32_16x16x32_bf16(af8, bf2, zero, 0, 0, 0);
      QSEL(C2, bq2, s22, kb2, kbv);
      f32x4 C3 = __builtin_amdgcn_mfma_f32_16x16x32_bf16(af8, bf3, zero, 0, 0, 0);
      QSEL(C3, bq3, s23, kb3, kbv);
    }

    // ---- cross-lane merge per pt (xor16, xor32), then pick own pt-group
#pragma unroll
    for (int m = 16; m <= 32; m <<= 1) {
      float ob0 = __shfl_xor(bq0, m, 64), o20 = __shfl_xor(s20, m, 64); int oi0 = __shfl_xor(kb0, m, 64);
      MERGE(bq0, s20, kb0, ob0, o20, oi0);
      float ob1 = __shfl_xor(bq1, m, 64), o21 = __shfl_xor(s21, m, 64); int oi1 = __shfl_xor(kb1, m, 64);
      MERGE(bq1, s21, kb1, ob1, o21, oi1);
      float ob2 = __shfl_xor(bq2, m, 64), o22 = __shfl_xor(s22, m, 64); int oi2 = __shfl_xor(kb2, m, 64);
      MERGE(bq2, s22, kb2, ob2, o22, oi2);
      float ob3 = __shfl_xor(bq3, m, 64), o23 = __shfl_xor(s23, m, 64); int oi3 = __shfl_xor(kb3, m, 64);
      MERGE(bq3, s23, kb3, ob3, o23, oi3);
    }
    const int myp = lane >> 4;
    float b2F = (myp == 0) ? s20 : (myp == 1) ? s21 : (myp == 2) ? s22 : s23;
    int   kbF = (myp == 0) ? kb0 : (myp == 1) ? kb1 : (myp == 2) ? kb2 : kb3;

    // ---- exact resolution of the winning quad (4 candidates, f32 = hi+lo)
    float rbest = -3.402823466e38f, rsec = -3.402823466e38f;
    int bidxF = kbF;
#pragma unroll
    for (int j = 0; j < 3 + 1; j++) {
      int k = kbF + j;
      int ch = (2*k) ^ (((2*k) >> 3) & 3);
      int cl = (2*k + 1) ^ (((2*k + 1) >> 3) & 3);
      int4 hv = *(const int4*)(ldsbuf + (size_t)ch*16);
      int4 lv = *(const int4*)(ldsbuf + (size_t)cl*16);
      float dot = 0.f;
      {
        float e;
        e = __uint_as_float(((unsigned)hv.x) << 16) + __uint_as_float(((unsigned)lv.x) << 16);
        dot = fmaf(encf[0], e, dot);
        e = __uint_as_float(((unsigned)hv.x) & 0xFFFF0000u) + __uint_as_float(((unsigned)lv.x) & 0xFFFF0000u);
        dot = fmaf(encf[1], e, dot);
        e = __uint_as_float(((unsigned)hv.y) << 16) + __uint_as_float(((unsigned)lv.y) << 16);
        dot = fmaf(encf[2], e, dot);
        e = __uint_as_float(((unsigned)hv.y) & 0xFFFF0000u) + __uint_as_float(((unsigned)lv.y) & 0xFFFF0000u);
        dot = fmaf(encf[3], e, dot);
        e = __uint_as_float(((unsigned)hv.z) << 16) + __uint_as_float(((unsigned)lv.z) << 16);
        dot = fmaf(encf[4], e, dot);
        e = __uint_as_float(((unsigned)hv.z) & 0xFFFF0000u) + __uint_as_float(((unsigned)lv.z) & 0xFFFF0000u);
        dot = fmaf(encf[5], e, dot);
        e = __uint_as_float(((unsigned)hv.w) << 16) + __uint_as_float(((unsigned)lv.w) << 16);
        dot = fmaf(encf[6], e, dot);
        e = __uint_as_float(((unsigned)hv.w) & 0xFFFF0000u) + __uint_as_float(((unsigned)lv.w) & 0xFFFF0000u);
        dot = fmaf(encf[7], e, dot);
      }
      if (dot > rbest) { rsec = rbest; rbest = dot; bidxF = k; }
      else             { rsec = fmaxf(rsec, dot); }
    }
    bool trigF = (rbest - fmaxf(b2F, rsec)) < MARGIN;

    // ---- near-tie: cooperative f64 rescan (wave-parallel, ~1K cyc/trigger)
    {
      unsigned long long bal = __ballot(trigF);
      while (bal) {
        int j = __builtin_ctzll(bal);
        bal &= bal - 1;
        double invb = __shfl(inv, j, 64);
        double encb[CD], se = 0.0;
#pragma unroll
        for (int c = 0; c < CD; c++) {
          encb[c] = __shfl(ze[c], j, 64) * invb;
          se = fma(encb[c], encb[c], se);
        }
        const double* __restrict__ cbr = cbn64 + (size_t)i*KCB*CD;
        const double* __restrict__ s64 = scbk64 + i*KCB;
        double bd = 1e300;
        int bk = 0;
#pragma unroll 2
        for (int it = 0; it < 16; it++) {
          int k = it*64 + lane;
          const double* row = cbr + (size_t)k*CD;
          double dot = 0.0;
#pragma unroll
          for (int c = 0; c < CD; c++) dot = fma(encb[c], row[c], dot);
          double dist = fma(-2.0, dot, se) + s64[k];
          if (dist < bd) { bd = dist; bk = k; }       // ascending k -> first index
        }
#pragma unroll
        for (int m = 1; m <= 32; m <<= 1) {
          double od = __shfl_xor(bd, m, 64);
          int    ok = __shfl_xor(bk, m, 64);
          bool take = (od < bd) || (od == bd && ok < bk);
          bd = take ? od : bd;
          bk = take ? ok : bk;
        }
        if (lane == j) bidxF = bk;
      }
    }

    // ---- gather raw codebook row
    const float4* __restrict__ qrow = (const float4*)(cb + (size_t)(i*KCB + bidxF)*CD);
    float4 q0 = qrow[0], q1 = qrow[1];
    double zq[CD] = {(double)q0.x, (double)q0.y, (double)q0.z, (double)q0.w,
                     (double)q1.x, (double)q1.y, (double)q1.z, (double)q1.w};

    // ---- losses
#pragma unroll
    for (int c = 0; c < CD; c++) {
      double dlt = ze[c] - zq[c];
      lacc = fma(dlt, dlt, lacc);
    }

    // ---- out_proj (f64) + residual update
#pragma unroll
    for (int d = 0; d < DD; d++) {
      double acc = bout64[i*DD + d];
#pragma unroll
      for (int c = 0; c < CD; c++)
        acc = fma(Wout64[(i*DD + d)*CD + c], zq[c], acc);
      r[d] -= acc;
    }

    // ---- codes
    out[CODES_OFF + (b*NCB + i)*TT + t] = (float)bidxF;
  }

  // ---- z_q = x - residual_final
#pragma unroll
  for (int d = 0; d < DD; d++)
    out[(b*DD + d)*TT + t] = (float)((double)x[(b*DD + d)*TT + t] - r[d]);

  // ---- deterministic loss reduction
#pragma unroll
  for (int off = 32; off > 0; off >>= 1)
    lacc += __shfl_down(lacc, off, 64);
  if ((threadIdx.x & 63) == 0) wsum[wv] = lacc;
  __syncthreads();
  if (threadIdx.x == 0) {
    double s = 0.0;
#pragma unroll
    for (int w = 0; w < 8; w++) s += wsum[w];
    loss_part[blockIdx.x] = s;
  }
}

__global__ void loss_final(const double* __restrict__ loss_part,
                           float* __restrict__ out) {
  __shared__ double sh[256];
  sh[threadIdx.x] = loss_part[threadIdx.x];   // 256 blocks -> 256 partials
  __syncthreads();
  for (int off = 128; off > 0; off >>= 1) {
    if (threadIdx.x < off) sh[threadIdx.x] += sh[threadIdx.x + off];
    __syncthreads();
  }
  if (threadIdx.x == 0) {
    double v = sh[0] / ((double)NCB * (double)BB * (double)CD * (double)TT);
    out[LOSS_OFF]     = (float)v;   // commit
    out[LOSS_OFF + 1] = (float)v;   // cb_loss (equal in forward value)
  }
}

extern "C" void kernel_launch(void* const* d_in, const int* in_sizes, int n_in,
                              void* d_out, int out_size, void* d_ws, size_t ws_size,
                              hipStream_t stream) {
  const float* x     = (const float*)d_in[0];
  const float* W_in  = (const float*)d_in[1];
  const float* b_in  = (const float*)d_in[2];
  const float* cb    = (const float*)d_in[3];
  const float* W_out = (const float*)d_in[4];
  const float* b_out = (const float*)d_in[5];
  float* out = (float*)d_out;

  char* ws = (char*)d_ws;
  unsigned* cbsplit = (unsigned*)(ws + OFF_CBSPLIT);
  double* cbn64  = (double*)(ws + OFF_CBN64);
  double* scbk64 = (double*)(ws + OFF_SCBK64);
  double* Win64  = (double*)(ws + OFF_WIN64);
  double* Wout64 = (double*)(ws + OFF_WOUT64);
  double* bin64  = (double*)(ws + OFF_BIN64);
  double* bout64 = (double*)(ws + OFF_BOUT64);
  double* loss_part = (double*)(ws + OFF_LOSSPART);

  prep_cb<<<(NCB*KCB + 255)/256, 256, 0, stream>>>(cb, cbsplit, cbn64, scbk64);
  prep_w<<<(NCB*CD*DD + 255)/256, 256, 0, stream>>>(W_in, b_in, W_out, b_out,
                                                    Win64, bin64, Wout64, bout64);
  rvq_kernel<<<256, 512, 0, stream>>>(x, cb, Win64, bin64, Wout64, bout64,
                                      cbsplit, cbn64, scbk64, out, loss_part);
  loss_final<<<1, 256, 0, stream>>>(loss_part, out);
}